// Round 13
// baseline (819.252 us; speedup 1.0000x reference)
//
#include <hip/hip_runtime.h>

// RNNLM: logits[T,B,V] = (scan_t sigmoid(h@H + emb[x]@I + b1)) @ U + b2 ; plus final h.
// V=32000 E=1024 Hd=1024 T=64 B=32.
// R13: fully fused rec+transpose+projection, deadlock-proof by capacity:
//   448 blocks x 256 thr, launch_bounds(256,2), 32KB LDS -> 2 blocks/CU
//   guaranteed -> all 448 co-resident regardless of dispatch order.
//   blocks 0..63   : recurrence (R6-proven bytes; sc1 h stores, cnt flag)
//   blocks 64..127 : Ut transpose, panel(256-col)-per-block, sc1 packed
//                    stores (cross-XCD visible in-kernel), single-writer
//                    sc1 pflag[125] per panel (no counting races)
//   blocks 128..447: 320 persistent proj workers over 4000 128x128 tiles,
//                    tm-major; tile waits cnt>=64*(4tm+4) && pflag[tn>>1],
//                    then proven gemm_f16 body (A=hs, B=Ut, NT C-stores).
// Workers are work-gated (8us/level vs 17us production) -> rare polling, hs
// read once per tile: avoids R7's per-step traffic on the latency path.
// gemm256 deleted - projection hides under the recurrence window.

typedef _Float16 f16;
typedef f16 f16x4 __attribute__((ext_vector_type(4)));
typedef f16 f16x8 __attribute__((ext_vector_type(8)));
typedef float f32x4 __attribute__((ext_vector_type(4)));

static constexpr int Vv = 32000, Ee = 1024, Hd = 1024, Tt = 64, Bb = 32;
static constexpr int Mm = Tt * Bb;  // 2048 rows (t*B+b)
static constexpr int NBR = 64;      // recurrence blocks
static constexpr int NBX = 64;      // transpose blocks
static constexpr int NBW = 320;     // projection worker blocks
static constexpr int NPAN = 125;    // 256-col Ut panels
static constexpr int NTM = 16, NTN = 250; // 128x128 proj tiles

// async global->LDS, 16B per lane; LDS dest = wave-uniform base + lane*16
#define GLOAD16(g, l)                                                          \
  __builtin_amdgcn_global_load_lds(                                            \
      (const __attribute__((address_space(1))) void*)(g),                      \
      (__attribute__((address_space(3))) void*)(l), 16, 0, 0)

// ---------------- prep kernels ----------------

__global__ void transpose_cvt(const float* __restrict__ in, f16* __restrict__ out,
                              int K, int N) {
  __shared__ float t[32][33];
  int n0 = blockIdx.x * 32, k0 = blockIdx.y * 32;
  int tx = threadIdx.x, ty = threadIdx.y; // (32,8)
#pragma unroll
  for (int i = 0; i < 32; i += 8)
    t[ty + i][tx] = in[(size_t)(k0 + ty + i) * N + n0 + tx];
  __syncthreads();
#pragma unroll
  for (int i = 0; i < 32; i += 8)
    out[(size_t)(n0 + ty + i) * K + k0 + tx] = (f16)t[tx][ty + i];
}

__global__ void gather_emb(const int* __restrict__ tok, const float* __restrict__ emb,
                           f16* __restrict__ xg) {
  int m = blockIdx.x;
  int b = m % Bb, t = m / Bb;
  int token = tok[b * Tt + t];
  const float* src = emb + (size_t)token * Ee;
  f16* dst = xg + (size_t)m * Ee;
  int e = threadIdx.x * 4;
  float4 v = *(const float4*)(src + e);
  f16x4 o = {(f16)v.x, (f16)v.y, (f16)v.z, (f16)v.w};
  *(f16x4*)(dst + e) = o;
}

__global__ void cvt_h0(const float* __restrict__ h0, f16* __restrict__ h0f) {
  int i = blockIdx.x * 256 + threadIdx.x;
  h0f[i] = (f16)h0[i];
}

// ---------------- small GEMM (xI): 128x128 tile, BK=64, proven R4 ----------------
__global__ __launch_bounds__(256) void gemm_f16(
    const f16* __restrict__ A, const f16* __restrict__ Bt,
    const float* __restrict__ bias, float* __restrict__ C, int M, int N, int K) {
  __shared__ __align__(16) f16 As[128 * 64];
  __shared__ __align__(16) f16 Bs[128 * 64];

  const int nwg = gridDim.x, bid = blockIdx.x;
  const int cpx = nwg >> 3;
  const int i = (bid & 7) * cpx + (bid >> 3);
  const int ntm = M >> 7;
  const int tm = i % ntm, tn = i / ntm;

  const int tid = threadIdx.x;
  const int lane = tid & 63, wid = tid >> 6;
  const int wm = wid >> 1, wn = wid & 1;

  const int srow = lane >> 3;
  const int sslot = (lane & 7) ^ srow;
  const f16* gA = A + (size_t)(tm * 128 + wid * 8 + srow) * K + sslot * 8;
  const f16* gB = Bt + (size_t)(tn * 128 + wid * 8 + srow) * K + sslot * 8;
  f16* lA = As + wid * 512;
  f16* lB = Bs + wid * 512;

  f32x4 acc[4][4] = {};
  const int r = lane & 15, kb = lane >> 4;

  for (int kc = 0; kc < K; kc += 64) {
    __syncthreads();
#pragma unroll
    for (int rr = 0; rr < 4; ++rr) {
      GLOAD16(gA + (size_t)rr * 32 * K + kc, lA + rr * 2048);
      GLOAD16(gB + (size_t)rr * 32 * K + kc, lB + rr * 2048);
    }
    __syncthreads();

#pragma unroll
    for (int kk = 0; kk < 2; ++kk) {
      f16x8 af[4], bf[4];
#pragma unroll
      for (int ii = 0; ii < 4; ++ii) {
        const int rowA = wm * 64 + ii * 16 + r;
        const int rowB = wn * 64 + ii * 16 + r;
        const int slot = ((kk * 4 + kb) ^ (r & 7)) * 8;
        af[ii] = *(const f16x8*)(As + rowA * 64 + slot);
        bf[ii] = *(const f16x8*)(Bs + rowB * 64 + slot);
      }
#pragma unroll
      for (int ii = 0; ii < 4; ++ii)
#pragma unroll
        for (int jj = 0; jj < 4; ++jj)
          acc[ii][jj] = __builtin_amdgcn_mfma_f32_16x16x32_f16(af[ii], bf[jj], acc[ii][jj], 0, 0, 0);
    }
  }

  const int col0 = tn * 128 + wn * 64, row0 = tm * 128 + wm * 64;
#pragma unroll
  for (int ii = 0; ii < 4; ++ii)
#pragma unroll
    for (int jj = 0; jj < 4; ++jj) {
      int c = col0 + jj * 16 + (lane & 15);
      int rbase = row0 + ii * 16 + (lane >> 4) * 4;
      float bv = bias ? bias[c] : 0.f;
#pragma unroll
      for (int rr = 0; rr < 4; ++rr)
        C[(size_t)(rbase + rr) * N + c] = acc[ii][jj][rr] + bv;
    }
}

// ---------------- fused: recurrence + Ut transpose + projection workers ----------------
__global__ __launch_bounds__(256, 2) void fused_all(
    const f16* __restrict__ Ht,    // H^T f16 [col][k]
    const float* __restrict__ xI,  // [T*B][Hd], includes b1
    const f16* __restrict__ h0f,   // [B][Hd] f16
    f16* __restrict__ hs,          // [T*B][Hd] f16
    float* __restrict__ hN,        // [B][Hd] f32 (final state -> d_out tail)
    int* __restrict__ flags,       // [0]=cnt, [64..188]=pflag[125]
    const float* __restrict__ Um,  // U f32 [Hd][Vv]
    f16* __restrict__ Ut,          // U^T f16 [Vv][Hd] (sc1-written)
    const float* __restrict__ b2,  // [V]
    float* __restrict__ out) {     // logits [T*B][V]
  __shared__ __align__(16) char smem[32768]; // role-carved
  const int tid = threadIdx.x;
  const int bid = blockIdx.x;
  int* cnt = flags;
  int* pflag = flags + 64;

  if (bid < NBR) {
    // ================= recurrence role (R6-proven bytes) =================
    float(*red)[512] = (float(*)[512])smem;
    const int lane = tid & 63, w = tid >> 6;
    const int bn = bid;
    const int r = lane & 15, kb = lane >> 4;
    const int colg = bn * 16 + r;

    f16x8 bH[8];
#pragma unroll
    for (int ks = 0; ks < 8; ++ks)
      bH[ks] = *(const f16x8*)(Ht + (size_t)colg * Hd + w * 256 + ks * 32 + kb * 8);

    const int eb = tid >> 3, ecp = tid & 7;

    for (int t = 0; t < Tt; ++t) {
      const f16* hp = t ? hs + (size_t)(t - 1) * Bb * Hd : h0f;
      const float2 xv = *(const float2*)(xI + (size_t)(t * Bb + eb) * Hd + bn * 16 + 2 * ecp);
      f32x4 acc[2] = {};
#pragma unroll
      for (int mt = 0; mt < 2; ++mt) {
        f16x8 af[8];
#pragma unroll
        for (int ks = 0; ks < 8; ++ks)
          af[ks] = *(const f16x8*)(hp + (size_t)(mt * 16 + r) * Hd + w * 256 + ks * 32 + kb * 8);
#pragma unroll
        for (int ks = 0; ks < 8; ++ks)
          acc[mt] = __builtin_amdgcn_mfma_f32_16x16x32_f16(af[ks], bH[ks], acc[mt], 0, 0, 0);
      }
#pragma unroll
      for (int mt = 0; mt < 2; ++mt)
#pragma unroll
        for (int q = 0; q < 4; ++q)
          red[w][mt * 256 + (kb * 4 + q) * 16 + r] = acc[mt][q];
      __syncthreads();

      {
        const float2 r0 = *(const float2*)&red[0][eb * 16 + 2 * ecp];
        const float2 r1 = *(const float2*)&red[1][eb * 16 + 2 * ecp];
        const float2 r2 = *(const float2*)&red[2][eb * 16 + 2 * ecp];
        const float2 r3 = *(const float2*)&red[3][eb * 16 + 2 * ecp];
        float v0 = r0.x + r1.x + r2.x + r3.x + xv.x;
        float v1 = r0.y + r1.y + r2.y + r3.y + xv.y;
        float s0 = 1.f / (1.f + __expf(-v0));
        float s1 = 1.f / (1.f + __expf(-v1));
        union { f16 h[2]; unsigned u; } pk;
        pk.h[0] = (f16)s0;
        pk.h[1] = (f16)s1;
        unsigned* dst = (unsigned*)(hs + (size_t)(t * Bb + eb) * Hd + bn * 16 + 2 * ecp);
        __hip_atomic_store(dst, pk.u, __ATOMIC_RELAXED, __HIP_MEMORY_SCOPE_AGENT);
        if (t == Tt - 1)
          *(float2*)(hN + (size_t)eb * Hd + bn * 16 + 2 * ecp) = make_float2(s0, s1);
      }

      __syncthreads(); // vmcnt(0) drained block-wide (incl. sc1 h stores)
      if (tid == 0)
        (void)__hip_atomic_fetch_add(cnt, 1, __ATOMIC_RELAXED, __HIP_MEMORY_SCOPE_AGENT);
      const int target = (t + 1) * NBR;
      while (__hip_atomic_load(cnt, __ATOMIC_RELAXED, __HIP_MEMORY_SCOPE_AGENT) < target)
        __builtin_amdgcn_s_sleep(1);
      asm volatile("" ::: "memory");
    }
  } else if (bid < NBR + NBX) {
    // ================= Ut transpose role (panel-per-block, sc1 stores) =================
    float(*tt)[33] = (float(*)[33])smem;
    const int j = bid - NBR;                 // 0..63
    const int tx = tid & 31, ty = tid >> 5;  // 32 x 8
    for (int pj = j; pj < NPAN; pj += NBX) {
      for (int tile = 0; tile < 256; ++tile) { // 8 n-tiles x 32 k-tiles
        const int n0 = pj * 256 + (tile & 7) * 32;
        const int k0 = (tile >> 3) * 32;
#pragma unroll
        for (int i = 0; i < 32; i += 8)
          tt[ty + i][tx] =
              __builtin_nontemporal_load(Um + (size_t)(k0 + ty + i) * Vv + n0 + tx);
        __syncthreads();
        if (tx < 16) {
#pragma unroll
          for (int i = 0; i < 32; i += 8) {
            union { f16 h[2]; unsigned u; } pk;
            pk.h[0] = (f16)tt[2 * tx][ty + i];
            pk.h[1] = (f16)tt[2 * tx + 1][ty + i];
            unsigned* dst = (unsigned*)(Ut + (size_t)(n0 + ty + i) * Hd + k0 + 2 * tx);
            __hip_atomic_store(dst, pk.u, __ATOMIC_RELAXED, __HIP_MEMORY_SCOPE_AGENT);
          }
        }
        __syncthreads();
      }
      // panel done: all sc1 stores drained at the barrier above; publish flag
      if (tid == 0)
        __hip_atomic_store(pflag + pj, 1, __ATOMIC_RELAXED, __HIP_MEMORY_SCOPE_AGENT);
    }
  } else {
    // ================= projection worker role (persistent, tm-major tiles) =================
    f16* As = (f16*)smem;
    f16* Bs = (f16*)(smem + 16384);
    const int wkr = bid - NBR - NBX;         // 0..319
    const int lane = tid & 63, wid = tid >> 6;
    const int wm = wid >> 1, wn = wid & 1;
    const int srow = lane >> 3;
    const int sslot = (lane & 7) ^ srow;
    const int r = lane & 15, kb = lane >> 4;
    f16* lA = As + wid * 512;
    f16* lB = Bs + wid * 512;

    for (int idx = wkr; idx < NTM * NTN; idx += NBW) {
      const int tm = idx / NTN, tn = idx % NTN;
      // gate: hs rows [128tm,128tm+128) ready (t=4tm+3 stored) AND Ut panel ready
      const int tgt = 64 * (4 * tm + 4);
      for (;;) {
        int c = __hip_atomic_load(cnt, __ATOMIC_RELAXED, __HIP_MEMORY_SCOPE_AGENT);
        int p = __hip_atomic_load(pflag + (tn >> 1), __ATOMIC_RELAXED, __HIP_MEMORY_SCOPE_AGENT);
        if (c >= tgt && p) break;
        __builtin_amdgcn_s_sleep(32);
      }
      asm volatile("" ::: "memory"); // no staging hoisted above the gate

      const f16* gA = hs + (size_t)(tm * 128 + wid * 8 + srow) * Hd + sslot * 8;
      const f16* gB = Ut + (size_t)(tn * 128 + wid * 8 + srow) * Hd + sslot * 8;
      f32x4 acc[4][4] = {};

      for (int kc = 0; kc < Hd; kc += 64) {
        __syncthreads();
#pragma unroll
        for (int rr = 0; rr < 4; ++rr) {
          GLOAD16(gA + (size_t)rr * 32 * Hd + kc, lA + rr * 2048);
          GLOAD16(gB + (size_t)rr * 32 * Hd + kc, lB + rr * 2048);
        }
        __syncthreads();

#pragma unroll
        for (int kk = 0; kk < 2; ++kk) {
          f16x8 af[4], bf[4];
#pragma unroll
          for (int ii = 0; ii < 4; ++ii) {
            const int rowA = wm * 64 + ii * 16 + r;
            const int rowB = wn * 64 + ii * 16 + r;
            const int slot = ((kk * 4 + kb) ^ (r & 7)) * 8;
            af[ii] = *(const f16x8*)(As + rowA * 64 + slot);
            bf[ii] = *(const f16x8*)(Bs + rowB * 64 + slot);
          }
#pragma unroll
          for (int ii = 0; ii < 4; ++ii)
#pragma unroll
            for (int jj = 0; jj < 4; ++jj)
              acc[ii][jj] = __builtin_amdgcn_mfma_f32_16x16x32_f16(af[ii], bf[jj], acc[ii][jj], 0, 0, 0);
        }
      }

      const int col0 = tn * 128 + wn * 64, row0 = tm * 128 + wm * 64;
#pragma unroll
      for (int ii = 0; ii < 4; ++ii)
#pragma unroll
        for (int jj = 0; jj < 4; ++jj) {
          int c = col0 + jj * 16 + (lane & 15);
          int rbase = row0 + ii * 16 + (lane >> 4) * 4;
          float bv = b2[c];
#pragma unroll
          for (int rr = 0; rr < 4; ++rr)
            __builtin_nontemporal_store(acc[ii][jj][rr] + bv,
                                        out + (size_t)(rbase + rr) * Vv + c);
        }
      __syncthreads(); // epilogue done before next tile's staging overwrites LDS
    }
  }
}

// ---------------- launcher ----------------
extern "C" void kernel_launch(void* const* d_in, const int* in_sizes, int n_in,
                              void* d_out, int out_size, void* d_ws, size_t ws_size,
                              hipStream_t stream) {
  const int* input_x = (const int*)d_in[0];
  const float* h0 = (const float*)d_in[1];
  const float* emb = (const float*)d_in[2];
  const float* Hm = (const float*)d_in[3];
  const float* Im = (const float*)d_in[4];
  const float* b1 = (const float*)d_in[5];
  const float* Um = (const float*)d_in[6];
  const float* b2 = (const float*)d_in[7];
  float* out = (float*)d_out;

  char* ws = (char*)d_ws;
  size_t off = 0;
  auto alloc = [&](size_t bytes) { void* p = ws + off; off = (off + bytes + 255) & ~(size_t)255; return p; };
  f16* Ut = (f16*)alloc((size_t)Vv * Hd * 2);
  f16* It = (f16*)alloc((size_t)Hd * Ee * 2);
  f16* Ht = (f16*)alloc((size_t)Hd * Hd * 2);
  f16* xg = (f16*)alloc((size_t)Mm * Ee * 2);
  float* xI = (float*)alloc((size_t)Mm * Hd * 4);
  f16* hs = (f16*)alloc((size_t)Mm * Hd * 2);
  f16* h0f = (f16*)alloc((size_t)Bb * Hd * 2);
  int* flags = (int*)alloc(1024); // [0]=cnt, [64..188]=pflag[125]
  (void)ws_size; (void)in_sizes; (void)n_in; (void)out_size;

  hipMemsetAsync(flags, 0, 1024, stream);

  // small preps (feed xI gemm / recurrence)
  transpose_cvt<<<dim3(Hd / 32, Ee / 32), dim3(32, 8), 0, stream>>>(Im, It, Ee, Hd);
  transpose_cvt<<<dim3(Hd / 32, Hd / 32), dim3(32, 8), 0, stream>>>(Hm, Ht, Hd, Hd);
  gather_emb<<<Mm, 256, 0, stream>>>(input_x, emb, xg);
  cvt_h0<<<(Bb * Hd) / 256, 256, 0, stream>>>(h0, h0f);

  // xI = xg @ I + b1   (M=2048, N=1024, K=1024), grid 128 (%8==0)
  gemm_f16<<<(Mm / 128) * (Hd / 128), 256, 0, stream>>>(xg, It, b1, xI, Mm, Hd, Ee);

  // fused: recurrence + Ut transpose + projection -> hs, final h, logits
  fused_all<<<NBR + NBX + NBW, 256, 0, stream>>>(
      Ht, xI, h0f, hs, out + (size_t)Mm * Vv, flags, Um, Ut, b2, out);
}

// Round 14
// 458.059 us; speedup vs baseline: 1.7885x; 1.7885x over previous
//
#include <hip/hip_runtime.h>

// RNNLM: logits[T,B,V] = (scan_t sigmoid(h@H + emb[x]@I + b1)) @ U + b2 ; plus final h.
// V=32000 E=1024 Hd=1024 T=64 B=32.
// R14: REVERT R13 fusion (sc1-written Ut is not L3-retained -> workers pulled
// ~1GB from HBM; fusion across the latency-critical recurrence is closed,
// twice-proven bad: R7, R13). Back to R12 (best, 466us) + ONE safe trim:
// the 4 serial prep launches (It/Ht transpose, gather, h0 cvt) merged into a
// single role-dispatched kernel -> ~3 launch boundaries removed from the
// serial prefix. Everything downstream byte-identical to R12.

typedef _Float16 f16;
typedef f16 f16x4 __attribute__((ext_vector_type(4)));
typedef f16 f16x8 __attribute__((ext_vector_type(8)));
typedef float f32x4 __attribute__((ext_vector_type(4)));

static constexpr int Vv = 32000, Ee = 1024, Hd = 1024, Tt = 64, Bb = 32;
static constexpr int Mm = Tt * Bb; // 2048 rows (t*B+b)
static constexpr int NBR = 64;     // recurrence blocks in combo
static constexpr int NBT = 192;    // transpose blocks in combo

// async global->LDS, 16B per lane; LDS dest = wave-uniform base + lane*16
#define GLOAD16(g, l)                                                          \
  __builtin_amdgcn_global_load_lds(                                            \
      (const __attribute__((address_space(1))) void*)(g),                      \
      (__attribute__((address_space(3))) void*)(l), 16, 0, 0)

// ---------------- merged prep kernel ----------------
// roles by block id: [0,1024) It tiles; [1024,2048) Ht tiles;
// [2048,4096) gather rows; [4096,4224) h0 cvt. 256 thr each.
__global__ __launch_bounds__(256) void prep_all(
    const float* __restrict__ Im, f16* __restrict__ It,
    const float* __restrict__ Hm, f16* __restrict__ Ht,
    const int* __restrict__ tok, const float* __restrict__ emb,
    f16* __restrict__ xg,
    const float* __restrict__ h0, f16* __restrict__ h0f) {
  __shared__ float t[32][33];
  const int tid = threadIdx.x;
  const int bid = blockIdx.x;

  if (bid < 2048) {
    // 32x32 transpose+cvt tile: out[n][k] = (f16) in[k][n], K=N=1024
    const float* in = (bid < 1024) ? Im : Hm;
    f16* out = (bid < 1024) ? It : Ht;
    const int tile = bid & 1023;
    const int n0 = (tile & 31) * 32, k0 = (tile >> 5) * 32;
    const int tx = tid & 31, ty = tid >> 5; // 32 x 8
#pragma unroll
    for (int i = 0; i < 32; i += 8)
      t[ty + i][tx] = in[(size_t)(k0 + ty + i) * 1024 + n0 + tx];
    __syncthreads();
#pragma unroll
    for (int i = 0; i < 32; i += 8)
      out[(size_t)(n0 + ty + i) * 1024 + k0 + tx] = (f16)t[tx][ty + i];
  } else if (bid < 4096) {
    // gather: xg[m][e] = (f16) emb[tok[m]][e], m = t*B+b, tokens [B][T]
    const int m = bid - 2048;
    const int b = m % Bb, tt2 = m / Bb;
    const int token = tok[b * Tt + tt2];
    const float* src = emb + (size_t)token * Ee;
    f16* dst = xg + (size_t)m * Ee;
    const int e = tid * 4;
    float4 v = *(const float4*)(src + e);
    f16x4 o = {(f16)v.x, (f16)v.y, (f16)v.z, (f16)v.w};
    *(f16x4*)(dst + e) = o;
  } else {
    const int i = (bid - 4096) * 256 + tid;
    h0f[i] = (f16)h0[i];
  }
}

// ---------------- small GEMM (xI): 128x128 tile, BK=64, proven R4 ----------------
__global__ __launch_bounds__(256) void gemm_f16(
    const f16* __restrict__ A, const f16* __restrict__ Bt,
    const float* __restrict__ bias, float* __restrict__ C, int M, int N, int K) {
  __shared__ __align__(16) f16 As[128 * 64];
  __shared__ __align__(16) f16 Bs[128 * 64];

  const int nwg = gridDim.x, bid = blockIdx.x;
  const int cpx = nwg >> 3;
  const int i = (bid & 7) * cpx + (bid >> 3);
  const int ntm = M >> 7;
  const int tm = i % ntm, tn = i / ntm;

  const int tid = threadIdx.x;
  const int lane = tid & 63, wid = tid >> 6;
  const int wm = wid >> 1, wn = wid & 1;

  const int srow = lane >> 3;
  const int sslot = (lane & 7) ^ srow;
  const f16* gA = A + (size_t)(tm * 128 + wid * 8 + srow) * K + sslot * 8;
  const f16* gB = Bt + (size_t)(tn * 128 + wid * 8 + srow) * K + sslot * 8;
  f16* lA = As + wid * 512;
  f16* lB = Bs + wid * 512;

  f32x4 acc[4][4] = {};
  const int r = lane & 15, kb = lane >> 4;

  for (int kc = 0; kc < K; kc += 64) {
    __syncthreads();
#pragma unroll
    for (int rr = 0; rr < 4; ++rr) {
      GLOAD16(gA + (size_t)rr * 32 * K + kc, lA + rr * 2048);
      GLOAD16(gB + (size_t)rr * 32 * K + kc, lB + rr * 2048);
    }
    __syncthreads();

#pragma unroll
    for (int kk = 0; kk < 2; ++kk) {
      f16x8 af[4], bf[4];
#pragma unroll
      for (int ii = 0; ii < 4; ++ii) {
        const int rowA = wm * 64 + ii * 16 + r;
        const int rowB = wn * 64 + ii * 16 + r;
        const int slot = ((kk * 4 + kb) ^ (r & 7)) * 8;
        af[ii] = *(const f16x8*)(As + rowA * 64 + slot);
        bf[ii] = *(const f16x8*)(Bs + rowB * 64 + slot);
      }
#pragma unroll
      for (int ii = 0; ii < 4; ++ii)
#pragma unroll
        for (int jj = 0; jj < 4; ++jj)
          acc[ii][jj] = __builtin_amdgcn_mfma_f32_16x16x32_f16(af[ii], bf[jj], acc[ii][jj], 0, 0, 0);
    }
  }

  const int col0 = tn * 128 + wn * 64, row0 = tm * 128 + wm * 64;
#pragma unroll
  for (int ii = 0; ii < 4; ++ii)
#pragma unroll
    for (int jj = 0; jj < 4; ++jj) {
      int c = col0 + jj * 16 + (lane & 15);
      int rbase = row0 + ii * 16 + (lane >> 4) * 4;
      float bv = bias ? bias[c] : 0.f;
#pragma unroll
      for (int rr = 0; rr < 4; ++rr)
        C[(size_t)(rbase + rr) * N + c] = acc[ii][jj][rr] + bv;
    }
}

// ---------------- big GEMM (projection): 256x256 8-phase ----------------
#define BAR __builtin_amdgcn_s_barrier()
#define LG0 asm volatile("s_waitcnt lgkmcnt(0)")

__global__ __launch_bounds__(512) void gemm256(
    const f16* __restrict__ A, const f16* __restrict__ Bt,
    const float* __restrict__ bias, float* __restrict__ C,
    int M, int N, int K) {
  __shared__ __align__(16) f16 sm[65536]; // 128 KiB

  // XCD-bijective chunking, tm-fastest (R6 proven form)
  const int nwg = gridDim.x, bid = blockIdx.x;
  const int cpx = nwg >> 3;
  const int ii = (bid & 7) * cpx + (bid >> 3);
  const int ntm = M >> 8;
  const int tm = ii % ntm, tn = ii / ntm;

  const int tid = threadIdx.x;
  const int lane = tid & 63, w = tid >> 6;
  const int wm = w >> 2, wn = w & 3;
  const int r = lane & 15, kb = lane >> 4;

  const int srow = tid >> 3;
  const int slot8 = ((tid & 7) ^ (srow & 7)) * 8;
  const f16* gA = A + (size_t)(tm * 256 + srow) * K + slot8;
  const f16* gB = Bt + (size_t)(tn * 256 + srow) * K + slot8;
  const int lw = w * 512; // per-wave LDS staging offset (f16)

  const int NK = K >> 6;

  f32x4 acc[8][4] = {};
  f16x8 a[4][2], b[4][2];

#define STG(kt, ab, R0)                                                        \
  do {                                                                         \
    const f16* gsrc = (ab) ? gB : gA;                                          \
    f16* lb = sm + ((kt) & 1) * 32768 + (ab) * 16384 + (R0) * 64 + lw;         \
    GLOAD16(gsrc + (size_t)(R0) * K + (kt) * 64, lb);                          \
    GLOAD16(gsrc + (size_t)((R0) + 64) * K + (kt) * 64, lb + 4096);            \
  } while (0)

#define LDA(MH)                                                                \
  _Pragma("unroll") for (int i = 0; i < 4; ++i)                                \
  _Pragma("unroll") for (int kk = 0; kk < 2; ++kk)                             \
      a[i][kk] = *(const f16x8*)(Abuf + (wm * 128 + (MH) * 64 + i * 16 + r) * 64 + \
                                 (((kk * 4 + kb) ^ (r & 7)) * 8));

#define LDB(J0)                                                                \
  _Pragma("unroll") for (int j = 0; j < 2; ++j)                                \
  _Pragma("unroll") for (int kk = 0; kk < 2; ++kk)                             \
      b[(J0) + j][kk] = *(const f16x8*)(Bbuf + (wn * 64 + ((J0) + j) * 16 + r) * 64 + \
                                        (((kk * 4 + kb) ^ (r & 7)) * 8));

#define MFMA_Q(MI0, J0)                                                        \
  __builtin_amdgcn_s_setprio(1);                                               \
  _Pragma("unroll") for (int mi = 0; mi < 4; ++mi)                             \
  _Pragma("unroll") for (int j = 0; j < 2; ++j)                                \
  _Pragma("unroll") for (int kk = 0; kk < 2; ++kk)                             \
      acc[(MI0) + mi][(J0) + j] = __builtin_amdgcn_mfma_f32_16x16x32_f16(      \
          a[mi][kk], b[(J0) + j][kk], acc[(MI0) + mi][(J0) + j], 0, 0, 0);     \
  __builtin_amdgcn_s_setprio(0);

  STG(0, 0, 0); STG(0, 0, 128);
  STG(0, 1, 0); STG(0, 1, 128);
  STG(1, 0, 0); STG(1, 0, 128);
  asm volatile("s_waitcnt vmcnt(4)");
  BAR;

  for (int k = 0; k < NK; ++k) {
    const f16* Abuf = sm + (k & 1) * 32768;
    const f16* Bbuf = Abuf + 16384;
    const int kn1 = (k + 1 == NK) ? 0 : k + 1;
    const int kn2 = (k + 2 >= NK) ? k + 2 - NK : k + 2;

    LDA(0); LDB(0);
    STG(kn1, 1, 0);
    BAR; LG0;
    MFMA_Q(0, 0);
    BAR;

    LDB(2);
    STG(kn1, 1, 128);
    BAR; LG0;
    MFMA_Q(0, 2);
    BAR;

    LDA(1);
    BAR; LG0;
    MFMA_Q(4, 2);
    BAR;

    STG(kn2, 0, 0); STG(kn2, 0, 128);
    BAR;
    MFMA_Q(4, 0);
    asm volatile("s_waitcnt vmcnt(4)");
    BAR;
  }

  // epilogue: D frag col=lane&15, row=(lane>>4)*4+reg; nontemporal (write-once)
#pragma unroll
  for (int mi = 0; mi < 8; ++mi)
#pragma unroll
    for (int j = 0; j < 4; ++j) {
      int c = tn * 256 + wn * 64 + j * 16 + r;
      int rbase = tm * 256 + wm * 128 + mi * 16 + kb * 4;
      float bv = bias[c];
#pragma unroll
      for (int q = 0; q < 4; ++q)
        __builtin_nontemporal_store(acc[mi][j][q] + bv,
                                    C + (size_t)(rbase + q) * N + c);
    }
#undef STG
#undef LDA
#undef LDB
#undef MFMA_Q
}

// ---------------- combo: recurrence (blocks 0..63) + throttled Ut transpose ----------------
__global__ __launch_bounds__(256) void rec_plus_transpose(
    const f16* __restrict__ Ht,    // H^T f16 [col][k]
    const float* __restrict__ xI,  // [T*B][Hd], includes b1
    const f16* __restrict__ h0f,   // [B][Hd] f16
    f16* __restrict__ hs,          // [T*B][Hd] f16
    float* __restrict__ hN,        // [B][Hd] f32
    int* __restrict__ cnt,
    const float* __restrict__ Um,  // U f32 [Hd][Vv]
    f16* __restrict__ Ut) {        // U^T f16 [Vv][Hd]
  __shared__ float red[4][512];    // recurrence reduce
  __shared__ float tt[32][33];     // transpose tile
  const int tid = threadIdx.x;

  if (blockIdx.x >= NBR) {
    // ---- transpose role: NT loads (read-once Um), CACHED stores (Ut -> L3,
    //      consumed by gemm256 right after), s_sleep throttle ----
    const int tb = blockIdx.x - NBR;           // 0..NBT-1
    const int tx = tid & 31, ty = tid >> 5;    // 32 x 8
    const int ntile_n = Vv / 32;               // 1000
    const int ntiles = ntile_n * (Hd / 32);    // 32000
    for (int tile = tb; tile < ntiles; tile += NBT) {
      const int n0 = (tile % ntile_n) * 32, k0 = (tile / ntile_n) * 32;
#pragma unroll
      for (int i = 0; i < 32; i += 8)
        tt[ty + i][tx] =
            __builtin_nontemporal_load(Um + (size_t)(k0 + ty + i) * Vv + n0 + tx);
      __syncthreads();
#pragma unroll
      for (int i = 0; i < 32; i += 8)
        Ut[(size_t)(n0 + ty + i) * Hd + k0 + tx] = (f16)tt[tx][ty + i];
      __syncthreads();
      __builtin_amdgcn_s_sleep(16); // ~0.43us/tile: 166 tiles/block ~ 200us spread
    }
    return;
  }

  // ---- recurrence role (R6-proven bytes; nb hardcoded to NBR) ----
  const int lane = tid & 63, w = tid >> 6;
  const int bn = blockIdx.x;
  const int r = lane & 15, kb = lane >> 4;
  const int colg = bn * 16 + r;

  f16x8 bH[8];
#pragma unroll
  for (int ks = 0; ks < 8; ++ks)
    bH[ks] = *(const f16x8*)(Ht + (size_t)colg * Hd + w * 256 + ks * 32 + kb * 8);

  const int eb = tid >> 3, ecp = tid & 7;

  for (int t = 0; t < Tt; ++t) {
    const f16* hp = t ? hs + (size_t)(t - 1) * Bb * Hd : h0f;
    // hoist xI off the post-barrier critical path
    const float2 xv = *(const float2*)(xI + (size_t)(t * Bb + eb) * Hd + bn * 16 + 2 * ecp);
    f32x4 acc[2] = {};
#pragma unroll
    for (int mt = 0; mt < 2; ++mt) {
      f16x8 af[8];
#pragma unroll
      for (int ks = 0; ks < 8; ++ks)
        af[ks] = *(const f16x8*)(hp + (size_t)(mt * 16 + r) * Hd + w * 256 + ks * 32 + kb * 8);
#pragma unroll
      for (int ks = 0; ks < 8; ++ks)
        acc[mt] = __builtin_amdgcn_mfma_f32_16x16x32_f16(af[ks], bH[ks], acc[mt], 0, 0, 0);
    }
#pragma unroll
    for (int mt = 0; mt < 2; ++mt)
#pragma unroll
      for (int q = 0; q < 4; ++q)
        red[w][mt * 256 + (kb * 4 + q) * 16 + r] = acc[mt][q];
    __syncthreads();

    {
      const float2 r0 = *(const float2*)&red[0][eb * 16 + 2 * ecp];
      const float2 r1 = *(const float2*)&red[1][eb * 16 + 2 * ecp];
      const float2 r2 = *(const float2*)&red[2][eb * 16 + 2 * ecp];
      const float2 r3 = *(const float2*)&red[3][eb * 16 + 2 * ecp];
      float v0 = r0.x + r1.x + r2.x + r3.x + xv.x;
      float v1 = r0.y + r1.y + r2.y + r3.y + xv.y;
      float s0 = 1.f / (1.f + __expf(-v0));
      float s1 = 1.f / (1.f + __expf(-v1));
      union { f16 h[2]; unsigned u; } pk;
      pk.h[0] = (f16)s0;
      pk.h[1] = (f16)s1;
      unsigned* dst = (unsigned*)(hs + (size_t)(t * Bb + eb) * Hd + bn * 16 + 2 * ecp);
      __hip_atomic_store(dst, pk.u, __ATOMIC_RELAXED, __HIP_MEMORY_SCOPE_AGENT);
      if (t == Tt - 1)
        *(float2*)(hN + (size_t)eb * Hd + bn * 16 + 2 * ecp) = make_float2(s0, s1);
    }

    // ---- grid barrier (R3/R6-proven): drain -> tid0 RMW -> all-thread poll ----
    __syncthreads(); // red reads done; vmcnt(0) drained block-wide (incl. sc1 stores)
    if (tid == 0)
      (void)__hip_atomic_fetch_add(cnt, 1, __ATOMIC_RELAXED, __HIP_MEMORY_SCOPE_AGENT);
    const int target = (t + 1) * NBR;
    while (__hip_atomic_load(cnt, __ATOMIC_RELAXED, __HIP_MEMORY_SCOPE_AGENT) < target)
      __builtin_amdgcn_s_sleep(1);
    asm volatile("" ::: "memory"); // no h-load hoisting above the poll
  }
}

// ---------------- launcher ----------------
extern "C" void kernel_launch(void* const* d_in, const int* in_sizes, int n_in,
                              void* d_out, int out_size, void* d_ws, size_t ws_size,
                              hipStream_t stream) {
  const int* input_x = (const int*)d_in[0];
  const float* h0 = (const float*)d_in[1];
  const float* emb = (const float*)d_in[2];
  const float* Hm = (const float*)d_in[3];
  const float* Im = (const float*)d_in[4];
  const float* b1 = (const float*)d_in[5];
  const float* Um = (const float*)d_in[6];
  const float* b2 = (const float*)d_in[7];
  float* out = (float*)d_out;

  char* ws = (char*)d_ws;
  size_t off = 0;
  auto alloc = [&](size_t bytes) { void* p = ws + off; off = (off + bytes + 255) & ~(size_t)255; return p; };
  f16* Ut = (f16*)alloc((size_t)Vv * Hd * 2);
  f16* It = (f16*)alloc((size_t)Hd * Ee * 2);
  f16* Ht = (f16*)alloc((size_t)Hd * Hd * 2);
  f16* xg = (f16*)alloc((size_t)Mm * Ee * 2);
  float* xI = (float*)alloc((size_t)Mm * Hd * 4);
  f16* hs = (f16*)alloc((size_t)Mm * Hd * 2);
  f16* h0f = (f16*)alloc((size_t)Bb * Hd * 2);
  int* cnt = (int*)alloc(256);
  (void)ws_size; (void)in_sizes; (void)n_in; (void)out_size;

  hipMemsetAsync(cnt, 0, sizeof(int), stream);

  // merged preps: It, Ht transposes + emb gather + h0 cvt in ONE launch
  prep_all<<<4224, 256, 0, stream>>>(Im, It, Hm, Ht, input_x, emb, xg, h0, h0f);

  // xI = xg @ I + b1   (M=2048, N=1024, K=1024), grid 128 (%8==0)
  gemm_f16<<<(Mm / 128) * (Hd / 128), 256, 0, stream>>>(xg, It, b1, xI, Mm, Hd, Ee);

  // combo: recurrence -> hs + final h; throttled Ut transpose on idle CUs
  rec_plus_transpose<<<NBR + NBT, 256, 0, stream>>>(
      Ht, xI, h0f, hs, out + (size_t)Mm * Vv, cnt, Um, Ut);

  // logits = hs @ U + b2   (M=2048, N=32000, K=1024), grid 1000 (%8==0)
  gemm256<<<(Mm / 256) * (Vv / 256), 512, 0, stream>>>(hs, Ut, b2, out, Mm, Vv, Hd);
}